// Round 18
// baseline (4324.583 us; speedup 1.0000x reference)
//
#include <hip/hip_runtime.h>
#include <hip/hip_bf16.h>

#define HIDN 512
#define EMBD 128
#define NB   1024
#define SL   48
#define NG   2048
#define KA2  1024   // A2 row = [ctx(512) | h(512)]

// d_out FLOAT32: [ output (B,L,H) | h_final (1,B,H) | c_final (1,B,H) ]
#define HPOS ((size_t)25165824)
#define CPOS ((size_t)25690112)

typedef __attribute__((ext_vector_type(8))) short short8v;
typedef __attribute__((ext_vector_type(4))) float f32x4;

__device__ __forceinline__ float sigmf(float x) { return 1.0f / (1.0f + expf(-x)); }
__device__ __forceinline__ short bfr(float x) {
  __hip_bfloat16 h = __float2bfloat16(x);
  return *(short*)&h;
}
__device__ __forceinline__ float bf2f(unsigned short u) {
  union { unsigned int i; float f; } c;
  c.i = ((unsigned int)u) << 16;
  return c.f;
}

// ---- W1p[n'][k]: gate-permuted n'=4j+g (r=g*512+j); k<512 ctx, k>=512 h -----------------
__global__ __launch_bounds__(256) void prep_w1p(const float* __restrict__ Wih,
                                                const float* __restrict__ Whh,
                                                short* __restrict__ W1p) {
  int idx = blockIdx.x * 256 + threadIdx.x;
  if (idx < NG * KA2) {
    int n = idx >> 10, k = idx & 1023;
    int j = n >> 2, g = n & 3, r = g * 512 + j;
    float w = (k < 512) ? Wih[(size_t)r * 640 + 128 + k] : Whh[(size_t)r * 512 + (k - 512)];
    W1p[idx] = bfr(w);
  }
}

// ---- Wxpb[n'][0:128] = bf16(W_ih[r][0:128]); bperm[n'] = b_ih[r]+b_hh[r] ----------------
__global__ __launch_bounds__(256) void prep_wxp(const float* __restrict__ Wih,
                                                const float* __restrict__ bih,
                                                const float* __restrict__ bhh,
                                                short* __restrict__ Wxpb,
                                                float* __restrict__ bperm) {
  int idx = blockIdx.x * 256 + threadIdx.x;
  if (idx < NG * EMBD) {
    int n = idx >> 7, k = idx & 127;
    int j = n >> 2, g = n & 3, r = g * 512 + j;
    Wxpb[idx] = bfr(Wih[(size_t)r * 640 + k]);
    if (k == 0) bperm[n] = bih[r] + bhh[r];
  }
}

__global__ __launch_bounds__(256) void prep_embb(const float* __restrict__ emb,
                                                 short* __restrict__ embbf) {
  int idx = blockIdx.x * 256 + threadIdx.x;
  if (idx < 640 * EMBD) {
    int v = idx >> 7;
    embbf[idx] = (v < 620) ? bfr(emb[idx]) : (short)0;
  }
}

__global__ __launch_bounds__(256) void prep_bf(const float* __restrict__ src,
                                               short* __restrict__ dst, int n) {
  int idx = blockIdx.x * 256 + threadIdx.x;
  if (idx < n) dst[idx] = bfr(src[idx]);
}

__global__ __launch_bounds__(256) void init2(const float* __restrict__ h0,
                                             const float* __restrict__ c0,
                                             short* __restrict__ A2,
                                             float* __restrict__ Hst,
                                             float* __restrict__ C) {
  int idx = blockIdx.x * 256 + threadIdx.x;
  int b = idx >> 9, k = idx & 511;
  A2[(size_t)b * KA2 + k] = 0;
  A2[(size_t)b * KA2 + 512 + k] = bfr(h0[idx]);
  Hst[idx] = h0[idx];
  C[idx] = c0[idx];
}

// ---- generalized pipelined MFMA NT GEMM, BK=64, LDS-staged coalesced C-write ------------
template <int BM, int BN, bool AF32, bool BF16_OUT, bool HAS_BIAS>
__global__ __launch_bounds__(256) void gemm_mfma(const void* __restrict__ Ap, int lda,
                                                 const short* __restrict__ B, int ldb,
                                                 const float* __restrict__ bias,
                                                 void* __restrict__ Cp, int ldc, int K) {
  constexpr int WC = (BM == 64) ? 2 : 4;     // wave cols
  constexpr int WTN = BN / WC, NF = WTN / 16;
  constexpr int NA = BM / 32;                // A uint4-chunks per thread
  constexpr int NBC = BN / 32;               // B uint4-chunks per thread
  constexpr int CPAD = BF16_OUT ? 8 : 4;
  constexpr int AB_B = (BM + BN) * 72 * 2;
  constexpr int C_B = BM * (BN + CPAD) * (BF16_OUT ? 2 : 4);
  constexpr int SB = AB_B > C_B ? AB_B : C_B;
  __shared__ __align__(16) char smraw[SB];
  short (*As)[72] = (short(*)[72])smraw;
  short (*Bs)[72] = (short(*)[72])(smraw + (size_t)BM * 144);
  const int tid = threadIdx.x;
  const int lane = tid & 63, wave = tid >> 6;
  const int wr = (BM == 64) ? (wave >> 1) : 0;
  const int wc = (BM == 64) ? (wave & 1) : wave;
  const int m0 = blockIdx.y * BM, n0 = blockIdx.x * BN;
  f32x4 acc[2][NF];
  #pragma unroll
  for (int i = 0; i < 2; ++i)
    #pragma unroll
    for (int j = 0; j < NF; ++j) acc[i][j] = (f32x4){0.f, 0.f, 0.f, 0.f};
  const int ar0 = tid >> 3, sc0 = (tid & 7) * 8;
  const int lr = lane & 15, lk = (lane >> 4) * 8;
  const int nk = K / 64;
  uint4 pa[AF32 ? 2 * NA : NA], pb[NBC];

#define LOADG(KT)                                                                        \
  {                                                                                      \
    if (AF32) {                                                                          \
      const float* A = (const float*)Ap;                                                 \
      _Pragma("unroll")                                                                  \
      for (int q = 0; q < NA; ++q) {                                                     \
        const float* sp = &A[(size_t)(m0 + ar0 + q * 32) * lda + (KT) * 64 + sc0];       \
        pa[2 * q] = *(const uint4*)sp;                                                   \
        pa[2 * q + 1] = *(const uint4*)(sp + 4);                                         \
      }                                                                                  \
    } else {                                                                             \
      const short* A = (const short*)Ap;                                                 \
      _Pragma("unroll")                                                                  \
      for (int q = 0; q < NA; ++q)                                                       \
        pa[q] = *(const uint4*)&A[(size_t)(m0 + ar0 + q * 32) * lda + (KT) * 64 + sc0];  \
    }                                                                                    \
    _Pragma("unroll")                                                                    \
    for (int q = 0; q < NBC; ++q)                                                        \
      pb[q] = *(const uint4*)&B[(size_t)(n0 + ar0 + q * 32) * ldb + (KT) * 64 + sc0];    \
  }
#define STOREL()                                                                         \
  {                                                                                      \
    if (AF32) {                                                                          \
      _Pragma("unroll")                                                                  \
      for (int q = 0; q < NA; ++q) {                                                     \
        const float* f0 = (const float*)&pa[2 * q];                                      \
        const float* f1 = (const float*)&pa[2 * q + 1];                                  \
        short8v v8;                                                                      \
        v8[0] = bfr(f0[0]); v8[1] = bfr(f0[1]); v8[2] = bfr(f0[2]); v8[3] = bfr(f0[3]);  \
        v8[4] = bfr(f1[0]); v8[5] = bfr(f1[1]); v8[6] = bfr(f1[2]); v8[7] = bfr(f1[3]);  \
        *(short8v*)&As[ar0 + q * 32][sc0] = v8;                                          \
      }                                                                                  \
    } else {                                                                             \
      _Pragma("unroll")                                                                  \
      for (int q = 0; q < NA; ++q) *(uint4*)&As[ar0 + q * 32][sc0] = pa[q];              \
    }                                                                                    \
    _Pragma("unroll")                                                                    \
    for (int q = 0; q < NBC; ++q) *(uint4*)&Bs[ar0 + q * 32][sc0] = pb[q];               \
  }

  LOADG(0);
  STOREL();
  __syncthreads();
  for (int kt = 0; kt < nk; ++kt) {
    if (kt + 1 < nk) LOADG(kt + 1);
    #pragma unroll
    for (int kk = 0; kk < 2; ++kk) {
      short8v a[2], b[NF];
      #pragma unroll
      for (int i = 0; i < 2; ++i)
        a[i] = *(const short8v*)&As[wr * 32 + i * 16 + lr][kk * 32 + lk];
      #pragma unroll
      for (int j = 0; j < NF; ++j)
        b[j] = *(const short8v*)&Bs[wc * WTN + j * 16 + lr][kk * 32 + lk];
      #pragma unroll
      for (int i = 0; i < 2; ++i)
        #pragma unroll
        for (int j = 0; j < NF; ++j)
          acc[i][j] = __builtin_amdgcn_mfma_f32_16x16x32_bf16(a[i], b[j], acc[i][j], 0, 0, 0);
    }
    __syncthreads();
    if (kt + 1 < nk) STOREL();
    __syncthreads();
  }
#undef LOADG
#undef STOREL

  // stage C (acc + bias) to LDS, then coalesced row writes
  short (*Cs)[BN + 8] = (short(*)[BN + 8])smraw;
  float (*Cf)[BN + 4] = (float(*)[BN + 4])smraw;
  #pragma unroll
  for (int i = 0; i < 2; ++i)
    #pragma unroll
    for (int j = 0; j < NF; ++j) {
      int col = wc * WTN + j * 16 + (lane & 15);
      float bv = HAS_BIAS ? bias[n0 + col] : 0.f;
      #pragma unroll
      for (int r = 0; r < 4; ++r) {
        int row = wr * 32 + i * 16 + (lane >> 4) * 4 + r;
        float v = acc[i][j][r] + bv;
        if (BF16_OUT) Cs[row][col] = bfr(v);
        else          Cf[row][col] = v;
      }
    }
  __syncthreads();
  constexpr int VECW = BF16_OUT ? 8 : 4;
  constexpr int VROW = BN / VECW;
  #pragma unroll 2
  for (int v = tid; v < BM * VROW; v += 256) {
    int row = v / VROW, cv = (v - row * VROW) * VECW;
    if (BF16_OUT)
      *(uint4*)&((short*)Cp)[(size_t)(m0 + row) * ldc + n0 + cv] = *(uint4*)&Cs[row][cv];
    else
      *(uint4*)&((float*)Cp)[(size_t)(m0 + row) * ldc + n0 + cv] = *(uint4*)&Cf[row][cv];
  }
}

// ---- FUSED gates GEMM + LSTM cell. BM=32, BN=128, grid 512 (2 blocks/CU) ----------------
__global__ __launch_bounds__(256) void gates_cell_f(const short* __restrict__ A2cur,
                                                    short* __restrict__ A2nxt,
                                                    const short* __restrict__ W1p,
                                                    const float* __restrict__ embW,
                                                    const int* __restrict__ seq,
                                                    const int* __restrict__ lens,
                                                    float* __restrict__ C,
                                                    float* __restrict__ Hst,
                                                    short* __restrict__ hcatbf,
                                                    float* __restrict__ outp, int t) {
  union SMem {
    struct { short A[32][72]; short B[128][72]; } s;
    float acc[32][132];
  };
  __shared__ __align__(16) SMem sm;
  const int tid = threadIdx.x;
  const int lane = tid & 63, wave = tid >> 6;
  const int bid = blockIdx.x;
  const int col = ((bid & 7) << 1) | ((bid >> 3) & 1);   // XCD stripe, 0..15
  const int row = bid >> 4;                              // 0..31
  const int m0 = row * 32, n0 = col * 128;
  f32x4 acc[2][2];
  #pragma unroll
  for (int i = 0; i < 2; ++i)
    #pragma unroll
    for (int j = 0; j < 2; ++j) acc[i][j] = (f32x4){0.f, 0.f, 0.f, 0.f};

  const int ar0 = tid >> 3, sc0 = (tid & 7) * 8;
  const int lr = lane & 15, lk = (lane >> 4) * 8;
  uint4 pa, pb[4];

#define GLOAD(KT)                                                                         \
  {                                                                                       \
    pa = *(const uint4*)&A2cur[(size_t)(m0 + ar0) * KA2 + (KT) * 64 + sc0];               \
    _Pragma("unroll")                                                                     \
    for (int q = 0; q < 4; ++q)                                                           \
      pb[q] = *(const uint4*)&W1p[(size_t)(n0 + ar0 + q * 32) * KA2 + (KT) * 64 + sc0];   \
  }
#define GSTORE()                                                                          \
  {                                                                                       \
    *(uint4*)&sm.s.A[ar0][sc0] = pa;                                                      \
    _Pragma("unroll")                                                                     \
    for (int q = 0; q < 4; ++q) *(uint4*)&sm.s.B[ar0 + q * 32][sc0] = pb[q];              \
  }

  GLOAD(0);
  GSTORE();
  __syncthreads();
  for (int kt = 0; kt < 16; ++kt) {
    if (kt + 1 < 16) GLOAD(kt + 1);
    #pragma unroll
    for (int kk = 0; kk < 2; ++kk) {
      short8v a[2], b[2];
      #pragma unroll
      for (int i = 0; i < 2; ++i)
        a[i] = *(const short8v*)&sm.s.A[i * 16 + lr][kk * 32 + lk];
      #pragma unroll
      for (int j = 0; j < 2; ++j)
        b[j] = *(const short8v*)&sm.s.B[wave * 32 + j * 16 + lr][kk * 32 + lk];
      #pragma unroll
      for (int i = 0; i < 2; ++i)
        #pragma unroll
        for (int j = 0; j < 2; ++j)
          acc[i][j] = __builtin_amdgcn_mfma_f32_16x16x32_bf16(a[i], b[j], acc[i][j], 0, 0, 0);
    }
    __syncthreads();
    if (kt + 1 < 16) GSTORE();
    __syncthreads();
  }
#undef GLOAD
#undef GSTORE

  #pragma unroll
  for (int i = 0; i < 2; ++i)
    #pragma unroll
    for (int j = 0; j < 2; ++j)
      #pragma unroll
      for (int r = 0; r < 4; ++r)
        sm.acc[i * 16 + (lane >> 4) * 4 + r][wave * 32 + j * 16 + (lane & 15)] =
            acc[i][j][r];
  __syncthreads();

  // fused LSTM cell: 8 threads/row, 4 units each (32 units per col-block)
  const int bl = tid >> 3;
  const int gb = m0 + bl;
  const int ju0 = (tid & 7) * 4;
  const int tok = seq[gb * SL + t];
  const bool am = t < lens[gb];
  const float* ewr = embW + (size_t)tok * NG + n0;
  #pragma unroll
  for (int u = 0; u < 4; ++u) {
    int jl = ju0 + u;
    int jg = (n0 >> 2) + jl;
    f32x4 ew = *(const f32x4*)&ewr[jl * 4];
    f32x4 g4 = *(const f32x4*)&sm.acc[bl][jl * 4];
    float gi = g4.x + ew.x, gf = g4.y + ew.y, gg = g4.z + ew.z, go = g4.w + ew.w;
    size_t cix = (size_t)gb * 512 + jg;
    float co = C[cix];
    float cn = sigmf(gf) * co + sigmf(gi) * tanhf(gg);
    float hn = sigmf(go) * tanhf(cn);
    hcatbf[(size_t)gb * 1024 + jg] = bfr(hn);
    hcatbf[(size_t)gb * 1024 + 512 + jg] = bfr(cn);
    short hv;
    if (am) { C[cix] = cn; Hst[cix] = hn; hv = bfr(hn); }
    else hv = A2cur[(size_t)gb * KA2 + 512 + jg];
    A2nxt[(size_t)gb * KA2 + 512 + jg] = hv;
    outp[((size_t)gb * SL + t) * 512 + jg] = am ? hn : 0.0f;
  }
}

// ---- attention: parallel scores (4 lanes/row) + softmax + ctx ---------------------------
template <bool ABF>
__global__ __launch_bounds__(256) void attn_row(const float* __restrict__ dec,
                                                const unsigned short* __restrict__ ef,
                                                const void* __restrict__ attnp,
                                                const float* __restrict__ mask,
                                                const int* __restrict__ lens,
                                                const short* __restrict__ A2cur,
                                                short* __restrict__ A2nxt,
                                                const float* __restrict__ v, int t) {
  __shared__ float sdec[HIDN], sv[HIDN], sa[SL], sraw[SL];
  const int b = blockIdx.x, tid = threadIdx.x;
  for (int k = tid; k < HIDN; k += 256) {
    sdec[k] = dec[(size_t)b * HIDN + k];
    sv[k] = v[k];
  }
  __syncthreads();
  if (tid < 192) {
    int tt = tid >> 2, q = tid & 3;
    const unsigned short* er = ef + ((size_t)b * SL + tt) * HIDN + q * 128;
    float s = 0.f;
    for (int k8 = 0; k8 < 128; k8 += 8) {
      uint4 u = *(const uint4*)&er[k8];
      const unsigned short* e8 = (const unsigned short*)&u;
      #pragma unroll
      for (int i = 0; i < 8; ++i) {
        int k = q * 128 + k8 + i;
        s += sv[k] * tanhf(bf2f(e8[i]) + sdec[k]);
      }
    }
    s += __shfl_xor(s, 1);
    s += __shfl_xor(s, 2);
    if (q == 0) sraw[tt] = s;
  }
  __syncthreads();
  if (tid < 64) {
    float s = (tid < SL) ? sraw[tid] : -1e30f;
    float mx = s;
    #pragma unroll
    for (int off = 32; off >= 1; off >>= 1) mx = fmaxf(mx, __shfl_xor(mx, off, 64));
    float e = (tid < SL) ? expf(s - mx) * mask[b * SL + tid] : 0.f;
    float sum = e;
    #pragma unroll
    for (int off = 32; off >= 1; off >>= 1) sum += __shfl_xor(sum, off, 64);
    if (tid < SL) sa[tid] = e / sum;
  }
  __syncthreads();
  const bool am = t < lens[b];
  for (int j = tid; j < HIDN; j += 256) {
    short cv;
    if (am) {
      float cx = 0.f;
      #pragma unroll
      for (int tt = 0; tt < SL; ++tt) {
        size_t ai = ((size_t)b * SL + tt) * HIDN + j;
        float av = ABF ? bf2f(((const unsigned short*)attnp)[ai])
                       : ((const float*)attnp)[ai];
        cx += sa[tt] * av;
      }
      cv = bfr(cx);
    } else {
      cv = A2cur[(size_t)b * KA2 + j];
    }
    A2nxt[(size_t)b * KA2 + j] = cv;
  }
}

__global__ __launch_bounds__(256) void fin2(const float* __restrict__ Hst,
                                            const float* __restrict__ C,
                                            float* __restrict__ outp) {
  int idx = blockIdx.x * 256 + threadIdx.x;
  outp[HPOS + idx] = Hst[idx];
  outp[CPOS + idx] = C[idx];
}

extern "C" void kernel_launch(void* const* d_in, const int* in_sizes, int n_in,
                              void* d_out, int out_size, void* d_ws, size_t ws_size,
                              hipStream_t stream) {
  (void)in_sizes; (void)n_in; (void)out_size;
  const int*   seq  = (const int*)d_in[0];
  const int*   lens = (const int*)d_in[1];
  const float* h0   = (const float*)d_in[2];
  const float* c0   = (const float*)d_in[3];
  const float* attn = (const float*)d_in[4];
  const float* mask = (const float*)d_in[5];
  const float* emb  = (const float*)d_in[6];
  const float* W_ih = (const float*)d_in[7];
  const float* W_hh = (const float*)d_in[8];
  const float* b_ih = (const float*)d_in[9];
  const float* b_hh = (const float*)d_in[10];
  const float* Wh   = (const float*)d_in[11];
  const float* Wdp  = (const float*)d_in[12];
  const float* bdp  = (const float*)d_in[13];
  const float* vv   = (const float*)d_in[14];
  float* outp = (float*)d_out;

  float* ws = (float*)d_ws;
  short* W1p    = (short*)(ws);                    // [0, 1048576)
  short* Wdpb   = (short*)(ws + 1048576);          // [1048576, 1310720)
  short* Whb    = (short*)(ws + 1310720);          // [1310720, 1441792)
  short* Wxpb   = (short*)(ws + 1441792);          // [1441792, 1572864)
  short* embbf  = (short*)(ws + 1572864);          // [1572864, 1613824)
  float* bperm  = ws + 1613824;                    // [1613824, 1615872)
  float* embW   = ws + 1615872;                    // [1615872, 2926592)
  unsigned short* ef = (unsigned short*)(ws + 2926592);  // [2926592, 15509504)
  short* A2b[2] = { (short*)(ws + 15509504), (short*)(ws + 16033792) };
  short* hcatbf = (short*)(ws + 16558080);
  float* Hst    = ws + 17082368;
  float* C      = ws + 17606656;
  float* dec    = ws + 18130944;                   // end 18655232 f = 74.6 MB
  short* attnbf = (short*)(ws + 18655232);         // optional, end 124.95 MB
  const bool useabf = ws_size >= (size_t)31238144 * 4;

  prep_w1p<<<(NG * KA2 + 255) / 256, 256, 0, stream>>>(W_ih, W_hh, W1p);
  prep_wxp<<<(NG * EMBD + 255) / 256, 256, 0, stream>>>(W_ih, b_ih, b_hh, Wxpb, bperm);
  prep_embb<<<(640 * EMBD + 255) / 256, 256, 0, stream>>>(emb, embbf);
  prep_bf<<<(512 * 1024 + 255) / 256, 256, 0, stream>>>(Wdp, Wdpb, 512 * 1024);
  prep_bf<<<(512 * 512 + 255) / 256, 256, 0, stream>>>(Wh, Whb, 512 * 512);
  if (useabf)
    prep_bf<<<(25165824 + 255) / 256, 256, 0, stream>>>(attn, attnbf, 25165824);
  // embW = embbf @ Wxpb^T + bperm  (640 x 2048, K=128)
  gemm_mfma<64, 128, false, false, true><<<dim3(NG / 128, 640 / 64), 256, 0, stream>>>(
      embbf, EMBD, Wxpb, EMBD, bperm, embW, NG, EMBD);
  // ef = attn @ Wh^T  (49152 x 512, K=512), bf16 out, BM=32
  gemm_mfma<32, 256, true, true, false><<<dim3(512 / 256, (NB * SL) / 32), 256, 0, stream>>>(
      attn, HIDN, Whb, HIDN, nullptr, ef, HIDN, HIDN);
  init2<<<(NB * HIDN) / 256, 256, 0, stream>>>(h0, c0, A2b[0], Hst, C);

  for (int t = 0; t < SL; ++t) {
    int cur = t & 1, nxt = cur ^ 1;
    gates_cell_f<<<512, 256, 0, stream>>>(A2b[cur], A2b[nxt], W1p, embW, seq, lens,
                                          C, Hst, hcatbf, outp, t);
    // dec = hcatbf @ Wdpb^T + bdp  (1024 x 512, K=1024), BM=32
    gemm_mfma<32, 64, false, false, true><<<dim3(HIDN / 64, NB / 32), 256, 0, stream>>>(
        hcatbf, 1024, Wdpb, 1024, bdp, dec, HIDN, 1024);
    if (useabf)
      attn_row<true><<<NB, 256, 0, stream>>>(dec, ef, attnbf, mask, lens,
                                             A2b[cur], A2b[nxt], vv, t);
    else
      attn_row<false><<<NB, 256, 0, stream>>>(dec, ef, attn, mask, lens,
                                              A2b[cur], A2b[nxt], vv, t);
  }
  fin2<<<(NB * HIDN) / 256, 256, 0, stream>>>(Hst, C, outp);
}

// Round 20
// 2929.052 us; speedup vs baseline: 1.4764x; 1.4764x over previous
//
#include <hip/hip_runtime.h>
#include <hip/hip_bf16.h>

#define HIDN 512
#define EMBD 128
#define NB   1024
#define SL   48
#define NG   2048
#define KA2  1024   // A2 row = [ctx(512) | h(512)]

// d_out FLOAT32: [ output (B,L,H) | h_final (1,B,H) | c_final (1,B,H) ]
#define HPOS ((size_t)25165824)
#define CPOS ((size_t)25690112)

typedef __attribute__((ext_vector_type(8))) short short8v;
typedef __attribute__((ext_vector_type(4))) float f32x4;

__device__ __forceinline__ float sigmf(float x) { return 1.0f / (1.0f + expf(-x)); }
__device__ __forceinline__ short bfr(float x) {
  __hip_bfloat16 h = __float2bfloat16(x);
  return *(short*)&h;
}
__device__ __forceinline__ float bf2f(unsigned short u) {
  union { unsigned int i; float f; } c;
  c.i = ((unsigned int)u) << 16;
  return c.f;
}

// ---- W1p[n'][k]: gate-permuted n'=4j+g (r=g*512+j); k<512 ctx, k>=512 h -----------------
__global__ __launch_bounds__(256) void prep_w1p(const float* __restrict__ Wih,
                                                const float* __restrict__ Whh,
                                                short* __restrict__ W1p) {
  int idx = blockIdx.x * 256 + threadIdx.x;
  if (idx < NG * KA2) {
    int n = idx >> 10, k = idx & 1023;
    int j = n >> 2, g = n & 3, r = g * 512 + j;
    float w = (k < 512) ? Wih[(size_t)r * 640 + 128 + k] : Whh[(size_t)r * 512 + (k - 512)];
    W1p[idx] = bfr(w);
  }
}

__global__ __launch_bounds__(256) void prep_wxp(const float* __restrict__ Wih,
                                                const float* __restrict__ bih,
                                                const float* __restrict__ bhh,
                                                short* __restrict__ Wxpb,
                                                float* __restrict__ bperm) {
  int idx = blockIdx.x * 256 + threadIdx.x;
  if (idx < NG * EMBD) {
    int n = idx >> 7, k = idx & 127;
    int j = n >> 2, g = n & 3, r = g * 512 + j;
    Wxpb[idx] = bfr(Wih[(size_t)r * 640 + k]);
    if (k == 0) bperm[n] = bih[r] + bhh[r];
  }
}

__global__ __launch_bounds__(256) void prep_embb(const float* __restrict__ emb,
                                                 short* __restrict__ embbf) {
  int idx = blockIdx.x * 256 + threadIdx.x;
  if (idx < 640 * EMBD) {
    int v = idx >> 7;
    embbf[idx] = (v < 620) ? bfr(emb[idx]) : (short)0;
  }
}

__global__ __launch_bounds__(256) void prep_bf(const float* __restrict__ src,
                                               short* __restrict__ dst, int n) {
  int idx = blockIdx.x * 256 + threadIdx.x;
  if (idx < n) dst[idx] = bfr(src[idx]);
}

__global__ __launch_bounds__(256) void init2(const float* __restrict__ h0,
                                             const float* __restrict__ c0,
                                             short* __restrict__ A2,
                                             float* __restrict__ Hst,
                                             float* __restrict__ C) {
  int idx = blockIdx.x * 256 + threadIdx.x;
  int b = idx >> 9, k = idx & 511;
  A2[(size_t)b * KA2 + k] = 0;
  A2[(size_t)b * KA2 + 512 + k] = bfr(h0[idx]);
  Hst[idx] = h0[idx];
  C[idx] = c0[idx];
}

// ---- double-buffered MFMA NT GEMM, BK=64, one barrier per K-iter, optional split-K ------
template <int BM, int BN, int KSPLIT, bool AF32, bool BF16_OUT, bool HAS_BIAS>
__global__ __launch_bounds__(256) void gemm_mfma2(const void* __restrict__ Ap, int lda,
                                                  const short* __restrict__ B, int ldb,
                                                  const float* __restrict__ bias,
                                                  void* __restrict__ Cp, int ldc, int K,
                                                  size_t cstride) {
  constexpr int WC = (BM == 64) ? 2 : 4;
  constexpr int WTN = BN / WC, NF = WTN / 16;
  constexpr int NA = BM / 32, NBC = BN / 32;
  constexpr int AB_B = 2 * (BM + BN) * 72 * 2;
  constexpr int C_B = BM * (BN + (BF16_OUT ? 8 : 4)) * (BF16_OUT ? 2 : 4);
  constexpr int SB = AB_B > C_B ? AB_B : C_B;
  __shared__ __align__(16) char smraw[SB];
  // As rows: [p*BM + r], Bs rows: [p*BN + r]  (single base pointers — no pointer arrays)
  short (*As)[72] = (short(*)[72])smraw;
  short (*Bs)[72] = (short(*)[72])(smraw + (size_t)2 * BM * 144);
  const int tid = threadIdx.x;
  const int lane = tid & 63, wave = tid >> 6;
  const int wr = (BM == 64) ? (wave >> 1) : 0;
  const int wc = (BM == 64) ? (wave & 1) : wave;
  const int kp = (KSPLIT > 1) ? ((int)blockIdx.y % KSPLIT) : 0;
  const int yb = (KSPLIT > 1) ? ((int)blockIdx.y / KSPLIT) : (int)blockIdx.y;
  const int m0 = yb * BM, n0 = blockIdx.x * BN;
  const int Keff = K / KSPLIT, koff = kp * Keff, nk = Keff / 64;
  f32x4 acc[2][NF];
  #pragma unroll
  for (int i = 0; i < 2; ++i)
    #pragma unroll
    for (int j = 0; j < NF; ++j) acc[i][j] = (f32x4){0.f, 0.f, 0.f, 0.f};
  const int ar0 = tid >> 3, sc0 = (tid & 7) * 8;
  const int lr = lane & 15, lk = (lane >> 4) * 8;
  uint4 pa[AF32 ? 2 * NA : NA], pb[NBC];

#define LOADG(KT)                                                                        \
  {                                                                                      \
    if (AF32) {                                                                          \
      const float* A = (const float*)Ap;                                                 \
      _Pragma("unroll")                                                                  \
      for (int q = 0; q < NA; ++q) {                                                     \
        const float* sp = &A[(size_t)(m0 + ar0 + q * 32) * lda + koff + (KT) * 64 + sc0];\
        pa[2 * q] = *(const uint4*)sp;                                                   \
        pa[2 * q + 1] = *(const uint4*)(sp + 4);                                         \
      }                                                                                  \
    } else {                                                                             \
      const short* A = (const short*)Ap;                                                 \
      _Pragma("unroll")                                                                  \
      for (int q = 0; q < NA; ++q)                                                       \
        pa[q] = *(const uint4*)&A[(size_t)(m0 + ar0 + q * 32) * lda + koff + (KT) * 64 + sc0]; \
    }                                                                                    \
    _Pragma("unroll")                                                                    \
    for (int q = 0; q < NBC; ++q)                                                        \
      pb[q] = *(const uint4*)&B[(size_t)(n0 + ar0 + q * 32) * ldb + koff + (KT) * 64 + sc0];   \
  }
#define STOREL(P)                                                                        \
  {                                                                                      \
    if (AF32) {                                                                          \
      _Pragma("unroll")                                                                  \
      for (int q = 0; q < NA; ++q) {                                                     \
        const float* f0 = (const float*)&pa[2 * q];                                      \
        const float* f1 = (const float*)&pa[2 * q + 1];                                  \
        short8v v8;                                                                      \
        v8[0] = bfr(f0[0]); v8[1] = bfr(f0[1]); v8[2] = bfr(f0[2]); v8[3] = bfr(f0[3]);  \
        v8[4] = bfr(f1[0]); v8[5] = bfr(f1[1]); v8[6] = bfr(f1[2]); v8[7] = bfr(f1[3]);  \
        *(short8v*)&As[(P) * BM + ar0 + q * 32][sc0] = v8;                               \
      }                                                                                  \
    } else {                                                                             \
      _Pragma("unroll")                                                                  \
      for (int q = 0; q < NA; ++q) *(uint4*)&As[(P) * BM + ar0 + q * 32][sc0] = pa[q];   \
    }                                                                                    \
    _Pragma("unroll")                                                                    \
    for (int q = 0; q < NBC; ++q) *(uint4*)&Bs[(P) * BN + ar0 + q * 32][sc0] = pb[q];    \
  }

  LOADG(0);
  STOREL(0);
  __syncthreads();
  for (int kt = 0; kt < nk; ++kt) {
    if (kt + 1 < nk) LOADG(kt + 1);
    const int p = kt & 1;
    #pragma unroll
    for (int kk = 0; kk < 2; ++kk) {
      short8v a[2], b[NF];
      #pragma unroll
      for (int i = 0; i < 2; ++i)
        a[i] = *(const short8v*)&As[p * BM + wr * 32 + i * 16 + lr][kk * 32 + lk];
      #pragma unroll
      for (int j = 0; j < NF; ++j)
        b[j] = *(const short8v*)&Bs[p * BN + wc * WTN + j * 16 + lr][kk * 32 + lk];
      #pragma unroll
      for (int i = 0; i < 2; ++i)
        #pragma unroll
        for (int j = 0; j < NF; ++j)
          acc[i][j] = __builtin_amdgcn_mfma_f32_16x16x32_bf16(a[i], b[j], acc[i][j], 0, 0, 0);
    }
    if (kt + 1 < nk) STOREL(p ^ 1);
    __syncthreads();
  }
#undef LOADG
#undef STOREL

  // stage C to LDS, coalesced writes
  short (*Cs)[BN + 8] = (short(*)[BN + 8])smraw;
  float (*Cf)[BN + 4] = (float(*)[BN + 4])smraw;
  __syncthreads();
  char* Cout = (char*)Cp + (size_t)kp * cstride;
  #pragma unroll
  for (int i = 0; i < 2; ++i)
    #pragma unroll
    for (int j = 0; j < NF; ++j) {
      int col = wc * WTN + j * 16 + (lane & 15);
      float bv = (HAS_BIAS && kp == 0) ? bias[n0 + col] : 0.f;
      #pragma unroll
      for (int r = 0; r < 4; ++r) {
        int row = wr * 32 + i * 16 + (lane >> 4) * 4 + r;
        float v = acc[i][j][r] + bv;
        if (BF16_OUT) Cs[row][col] = bfr(v);
        else          Cf[row][col] = v;
      }
    }
  __syncthreads();
  constexpr int VECW = BF16_OUT ? 8 : 4;
  constexpr int VROW = BN / VECW;
  for (int v = tid; v < BM * VROW; v += 256) {
    int row = v / VROW, cv = (v - row * VROW) * VECW;
    if (BF16_OUT)
      *(uint4*)&((short*)Cout)[(size_t)(m0 + row) * ldc + n0 + cv] = *(uint4*)&Cs[row][cv];
    else
      *(uint4*)&((float*)Cout)[(size_t)(m0 + row) * ldc + n0 + cv] = *(uint4*)&Cf[row][cv];
  }
}

// ---- FUSED gates GEMM + LSTM cell. BM=32, BN=64, grid 1024 (4 blocks/CU), dbuf ----------
__global__ __launch_bounds__(256) void gates_cell_f(const short* __restrict__ A2cur,
                                                    short* __restrict__ A2nxt,
                                                    const short* __restrict__ W1p,
                                                    const float* __restrict__ embW,
                                                    const int* __restrict__ seq,
                                                    const int* __restrict__ lens,
                                                    float* __restrict__ C,
                                                    float* __restrict__ Hst,
                                                    short* __restrict__ hcatbf,
                                                    float* __restrict__ outp, int t) {
  union SMem {
    struct { short A[2 * 32][72]; short B[2 * 64][72]; } s;
    float acc[32][68];
  };
  __shared__ __align__(16) SMem sm;
  const int tid = threadIdx.x;
  const int lane = tid & 63, wave = tid >> 6;
  const int bid = blockIdx.x;
  const int c = (bid & 7) + 8 * ((bid >> 3) & 3);   // XCD-stable col 0..31
  const int row = bid >> 5;                         // 0..31
  const int m0 = row * 32, n0 = c * 64;
  f32x4 acc[2];
  acc[0] = (f32x4){0.f, 0.f, 0.f, 0.f};
  acc[1] = (f32x4){0.f, 0.f, 0.f, 0.f};
  const int ar0 = tid >> 3, sc0 = (tid & 7) * 8;
  const int lr = lane & 15, lk = (lane >> 4) * 8;
  uint4 pa, pb[2];

#define GLOAD(KT)                                                                         \
  {                                                                                       \
    pa = *(const uint4*)&A2cur[(size_t)(m0 + ar0) * KA2 + (KT) * 64 + sc0];               \
    _Pragma("unroll")                                                                     \
    for (int q = 0; q < 2; ++q)                                                           \
      pb[q] = *(const uint4*)&W1p[(size_t)(n0 + ar0 + q * 32) * KA2 + (KT) * 64 + sc0];   \
  }
#define GSTORE(P)                                                                         \
  {                                                                                       \
    *(uint4*)&sm.s.A[(P) * 32 + ar0][sc0] = pa;                                           \
    _Pragma("unroll")                                                                     \
    for (int q = 0; q < 2; ++q) *(uint4*)&sm.s.B[(P) * 64 + ar0 + q * 32][sc0] = pb[q];   \
  }

  GLOAD(0);
  GSTORE(0);
  __syncthreads();
  for (int kt = 0; kt < 16; ++kt) {
    if (kt + 1 < 16) GLOAD(kt + 1);
    const int p = kt & 1;
    #pragma unroll
    for (int kk = 0; kk < 2; ++kk) {
      short8v a0 = *(const short8v*)&sm.s.A[p * 32 + lr][kk * 32 + lk];
      short8v a1 = *(const short8v*)&sm.s.A[p * 32 + 16 + lr][kk * 32 + lk];
      short8v b  = *(const short8v*)&sm.s.B[p * 64 + wave * 16 + lr][kk * 32 + lk];
      acc[0] = __builtin_amdgcn_mfma_f32_16x16x32_bf16(a0, b, acc[0], 0, 0, 0);
      acc[1] = __builtin_amdgcn_mfma_f32_16x16x32_bf16(a1, b, acc[1], 0, 0, 0);
    }
    if (kt + 1 < 16) GSTORE(p ^ 1);
    __syncthreads();
  }
#undef GLOAD
#undef GSTORE

  __syncthreads();
  #pragma unroll
  for (int i = 0; i < 2; ++i)
    #pragma unroll
    for (int r = 0; r < 4; ++r)
      sm.acc[i * 16 + (lane >> 4) * 4 + r][wave * 16 + (lane & 15)] = acc[i][r];
  __syncthreads();

  // fused cell: 8 threads/row, 2 units each (16 units in this col-block)
  const int bl = tid >> 3;
  const int gb = m0 + bl;
  const int ju0 = (tid & 7) * 2;
  const int tok = seq[gb * SL + t];
  const bool am = t < lens[gb];
  const float* ewr = embW + (size_t)tok * NG + n0;
  #pragma unroll
  for (int u = 0; u < 2; ++u) {
    int jl = ju0 + u;
    int jg = c * 16 + jl;
    f32x4 ew = *(const f32x4*)&ewr[jl * 4];
    f32x4 g4 = *(const f32x4*)&sm.acc[bl][jl * 4];
    float gi = g4.x + ew.x, gf = g4.y + ew.y, gg = g4.z + ew.z, go = g4.w + ew.w;
    size_t cix = (size_t)gb * 512 + jg;
    float co = C[cix];
    float cn = sigmf(gf) * co + sigmf(gi) * tanhf(gg);
    float hn = sigmf(go) * tanhf(cn);
    hcatbf[(size_t)gb * 1024 + jg] = bfr(hn);
    hcatbf[(size_t)gb * 1024 + 512 + jg] = bfr(cn);
    short hv;
    if (am) { C[cix] = cn; Hst[cix] = hn; hv = bfr(hn); }
    else hv = A2cur[(size_t)gb * KA2 + 512 + jg];
    A2nxt[(size_t)gb * KA2 + 512 + jg] = hv;
    outp[((size_t)gb * SL + t) * 512 + jg] = am ? hn : 0.0f;
  }
}

// ---- attention: dec = sum of split-K partials; scores + softmax + ctx -------------------
template <bool ABF>
__global__ __launch_bounds__(256) void attn_row(const float* __restrict__ decP,
                                                const unsigned short* __restrict__ ef,
                                                const void* __restrict__ attnp,
                                                const float* __restrict__ mask,
                                                const int* __restrict__ lens,
                                                const short* __restrict__ A2cur,
                                                short* __restrict__ A2nxt,
                                                const float* __restrict__ v, int t) {
  __shared__ float sdec[HIDN], sv[HIDN], sa[SL], sraw[SL];
  const int b = blockIdx.x, tid = threadIdx.x;
  for (int k = tid; k < HIDN; k += 256) {
    sdec[k] = decP[(size_t)b * HIDN + k] + decP[524288 + (size_t)b * HIDN + k];
    sv[k] = v[k];
  }
  __syncthreads();
  if (tid < 192) {
    int tt = tid >> 2, q = tid & 3;
    const unsigned short* er = ef + ((size_t)b * SL + tt) * HIDN + q * 128;
    float s = 0.f;
    for (int k8 = 0; k8 < 128; k8 += 8) {
      uint4 u = *(const uint4*)&er[k8];
      const unsigned short* e8 = (const unsigned short*)&u;
      #pragma unroll
      for (int i = 0; i < 8; ++i) {
        int k = q * 128 + k8 + i;
        s += sv[k] * tanhf(bf2f(e8[i]) + sdec[k]);
      }
    }
    s += __shfl_xor(s, 1);
    s += __shfl_xor(s, 2);
    if (q == 0) sraw[tt] = s;
  }
  __syncthreads();
  if (tid < 64) {
    float s = (tid < SL) ? sraw[tid] : -1e30f;
    float mx = s;
    #pragma unroll
    for (int off = 32; off >= 1; off >>= 1) mx = fmaxf(mx, __shfl_xor(mx, off, 64));
    float e = (tid < SL) ? expf(s - mx) * mask[b * SL + tid] : 0.f;
    float sum = e;
    #pragma unroll
    for (int off = 32; off >= 1; off >>= 1) sum += __shfl_xor(sum, off, 64);
    if (tid < SL) sa[tid] = e / sum;
  }
  __syncthreads();
  const bool am = t < lens[b];
  for (int j = tid; j < HIDN; j += 256) {
    short cv;
    if (am) {
      float cx = 0.f;
      #pragma unroll
      for (int tt = 0; tt < SL; ++tt) {
        size_t ai = ((size_t)b * SL + tt) * HIDN + j;
        float av = ABF ? bf2f(((const unsigned short*)attnp)[ai])
                       : ((const float*)attnp)[ai];
        cx += sa[tt] * av;
      }
      cv = bfr(cx);
    } else {
      cv = A2cur[(size_t)b * KA2 + j];
    }
    A2nxt[(size_t)b * KA2 + j] = cv;
  }
}

__global__ __launch_bounds__(256) void fin2(const float* __restrict__ Hst,
                                            const float* __restrict__ C,
                                            float* __restrict__ outp) {
  int idx = blockIdx.x * 256 + threadIdx.x;
  outp[HPOS + idx] = Hst[idx];
  outp[CPOS + idx] = C[idx];
}

extern "C" void kernel_launch(void* const* d_in, const int* in_sizes, int n_in,
                              void* d_out, int out_size, void* d_ws, size_t ws_size,
                              hipStream_t stream) {
  (void)in_sizes; (void)n_in; (void)out_size;
  const int*   seq  = (const int*)d_in[0];
  const int*   lens = (const int*)d_in[1];
  const float* h0   = (const float*)d_in[2];
  const float* c0   = (const float*)d_in[3];
  const float* attn = (const float*)d_in[4];
  const float* mask = (const float*)d_in[5];
  const float* emb  = (const float*)d_in[6];
  const float* W_ih = (const float*)d_in[7];
  const float* W_hh = (const float*)d_in[8];
  const float* b_ih = (const float*)d_in[9];
  const float* b_hh = (const float*)d_in[10];
  const float* Wh   = (const float*)d_in[11];
  const float* Wdp  = (const float*)d_in[12];
  const float* bdp  = (const float*)d_in[13];
  const float* vv   = (const float*)d_in[14];
  float* outp = (float*)d_out;

  float* ws = (float*)d_ws;
  short* W1p    = (short*)(ws);                    // [0, 1048576)
  short* Wdpb   = (short*)(ws + 1048576);          // [1048576, 1310720)
  short* Whb    = (short*)(ws + 1310720);          // [1310720, 1441792)
  short* Wxpb   = (short*)(ws + 1441792);          // [1441792, 1572864)
  short* embbf  = (short*)(ws + 1572864);          // [1572864, 1613824)
  float* bperm  = ws + 1613824;                    // [1613824, 1615872)
  float* embW   = ws + 1615872;                    // [1615872, 2926592)
  unsigned short* ef = (unsigned short*)(ws + 2926592);  // [2926592, 15509504)
  short* A2b[2] = { (short*)(ws + 15509504), (short*)(ws + 16033792) };
  short* hcatbf = (short*)(ws + 16558080);
  float* Hst    = ws + 17082368;
  float* C      = ws + 17606656;
  float* decP   = ws + 18130944;                   // 2 x 524288 -> end 19179520 (76.7 MB)
  short* attnbf = (short*)(ws + 19179520);         // optional, end 101.9 MB
  const bool useabf = ws_size >= (size_t)25470976 * 4;

  prep_w1p<<<(NG * KA2 + 255) / 256, 256, 0, stream>>>(W_ih, W_hh, W1p);
  prep_wxp<<<(NG * EMBD + 255) / 256, 256, 0, stream>>>(W_ih, b_ih, b_hh, Wxpb, bperm);
  prep_embb<<<(640 * EMBD + 255) / 256, 256, 0, stream>>>(emb, embbf);
  prep_bf<<<(512 * 1024 + 255) / 256, 256, 0, stream>>>(Wdp, Wdpb, 512 * 1024);
  prep_bf<<<(512 * 512 + 255) / 256, 256, 0, stream>>>(Wh, Whb, 512 * 512);
  if (useabf)
    prep_bf<<<(25165824 + 255) / 256, 256, 0, stream>>>(attn, attnbf, 25165824);
  // embW = embbf @ Wxpb^T + bperm  (640 x 2048, K=128)
  gemm_mfma2<64, 128, 1, false, false, true><<<dim3(NG / 128, 640 / 64), 256, 0, stream>>>(
      embbf, EMBD, Wxpb, EMBD, bperm, embW, NG, EMBD, 0);
  // ef = attn @ Wh^T  (49152 x 512, K=512), bf16 out, BM=64/BN=256
  if (useabf)
    gemm_mfma2<64, 256, 1, false, true, false><<<dim3(2, 768), 256, 0, stream>>>(
        attnbf, HIDN, Whb, HIDN, nullptr, ef, HIDN, HIDN, 0);
  else
    gemm_mfma2<64, 256, 1, true, true, false><<<dim3(2, 768), 256, 0, stream>>>(
        attn, HIDN, Whb, HIDN, nullptr, ef, HIDN, HIDN, 0);
  init2<<<(NB * HIDN) / 256, 256, 0, stream>>>(h0, c0, A2b[0], Hst, C);

  for (int t = 0; t < SL; ++t) {
    int cur = t & 1, nxt = cur ^ 1;
    gates_cell_f<<<1024, 256, 0, stream>>>(A2b[cur], A2b[nxt], W1p, embW, seq, lens,
                                           C, Hst, hcatbf, outp, t);
    // decP[kp] = hcatbf @ Wdpb^T (+bdp on kp=0), split-K=2, 512 blocks
    gemm_mfma2<32, 64, 2, false, false, true><<<dim3(HIDN / 64, 64), 256, 0, stream>>>(
        hcatbf, 1024, Wdpb, 1024, bdp, decP, HIDN, 1024, (size_t)524288 * 4);
    if (useabf)
      attn_row<true><<<NB, 256, 0, stream>>>(decP, ef, attnbf, mask, lens,
                                             A2b[cur], A2b[nxt], vv, t);
    else
      attn_row<false><<<NB, 256, 0, stream>>>(decP, ef, attn, mask, lens,
                                              A2b[cur], A2b[nxt], vv, t);
  }
  fin2<<<(NB * HIDN) / 256, 256, 0, stream>>>(Hst, C, outp);
}